// Round 6
// baseline (238.128 us; speedup 1.0000x reference)
//
#include <hip/hip_runtime.h>
#include <math.h>

#define D 64
#define K 512
#define N_TOK (32 * 4096)            // 131072 tokens
#define TOK 64                       // tokens per block
#define BLK 256                      // 4 k-quarters per token

// output layout (all f32, concatenated in reference return order)
#define Q_OFF    0
#define LOSS_OFF 8388608
#define PERP_OFF 8388609
#define ENC_OFF  8388610
#define MIND_OFF 8519682

// ws layout (floats): [0..511] b2[k] = np-f32 sum(e_k^2) ; [512] S_sq ; [513] S_mind ; [514..1025] counts(int)

// numpy pairwise_sum, n=64, scalar 8-accumulator path, on fl(x_i*x_i).
__device__ __forceinline__ float np_sumsq64(const float* x) {
    float r[8];
    #pragma unroll
    for (int j = 0; j < 8; ++j) r[j] = __fmul_rn(x[j], x[j]);
    #pragma unroll
    for (int i = 8; i < 64; i += 8) {
        #pragma unroll
        for (int j = 0; j < 8; ++j)
            r[j] = __fadd_rn(r[j], __fmul_rn(x[i + j], x[i + j]));
    }
    float l = __fadd_rn(__fadd_rn(r[0], r[1]), __fadd_rn(r[2], r[3]));
    float h = __fadd_rn(__fadd_rn(r[4], r[5]), __fadd_rn(r[6], r[7]));
    return __fadd_rn(l, h);
}

__global__ void vq_prep(const float* __restrict__ ew, float* __restrict__ b2) {
    int k = threadIdx.x;
    if (k < K) b2[k] = np_sumsq64(ew + (size_t)k * D);
}

// 64 tokens/block, 4-way k-split (128 codes per quarter), 8 codes per
// z-chunk so each ds_read_b128 feeds 32 FMAs (DS pipe ~half of VALU).
// (256,6): <=85 VGPR -> ~6 blocks/CU with 20.7 KB LDS -> 24 waves/CU.
__global__ __launch_bounds__(BLK, 6) void vq_main(
    const float* __restrict__ z, const float* __restrict__ ew,
    const float* __restrict__ b2, float* __restrict__ out,
    float* __restrict__ gsum, int* __restrict__ gcnt)
{
    __shared__ float4 zl[16 * TOK];          // 16 KB, slot = dc*TOK + (tok ^ (dc&7))
    __shared__ float  s_bd[4][TOK];
    __shared__ int    s_bk[4][TOK];
    __shared__ int    s_fbk[TOK];
    __shared__ int    s_cnt[K];

    const int tid = threadIdx.x;
    s_cnt[tid] = 0; s_cnt[tid + BLK] = 0;

    // ---- stage z tile: coalesced global read, swizzled LDS write ----
    {
        const float4* zg = (const float4*)z + (size_t)blockIdx.x * (TOK * 16);
        #pragma unroll
        for (int i = 0; i < 4; ++i) {
            int idx = i * BLK + tid;           // 0..1023 float4s of the tile
            float4 v = zg[idx];
            int tok = idx >> 4, dc = idx & 15;
            zl[dc * TOK + (tok ^ (dc & 7))] = v;
        }
    }
    __syncthreads();

    const int h = tid >> 6;                    // k-quarter 0..3
    const int t = tid & (TOK - 1);             // token within block

    int tx[8];
    #pragma unroll
    for (int j = 0; j < 8; ++j) tx[j] = t ^ j;

    // a_n = np.sum(z^2) in numpy's exact order, sourced from LDS
    float an;
    {
        float r[8];
        #pragma unroll
        for (int c = 0; c < 16; ++c) {
            float4 v = zl[c * TOK + tx[c & 7]];
            int j0 = (c & 1) * 4;
            if (c < 2) {
                r[j0]   = __fmul_rn(v.x, v.x); r[j0+1] = __fmul_rn(v.y, v.y);
                r[j0+2] = __fmul_rn(v.z, v.z); r[j0+3] = __fmul_rn(v.w, v.w);
            } else {
                r[j0]   = __fadd_rn(r[j0],   __fmul_rn(v.x, v.x));
                r[j0+1] = __fadd_rn(r[j0+1], __fmul_rn(v.y, v.y));
                r[j0+2] = __fadd_rn(r[j0+2], __fmul_rn(v.z, v.z));
                r[j0+3] = __fadd_rn(r[j0+3], __fmul_rn(v.w, v.w));
            }
        }
        float l = __fadd_rn(__fadd_rn(r[0], r[1]), __fadd_rn(r[2], r[3]));
        float hh = __fadd_rn(__fadd_rn(r[4], r[5]), __fadd_rn(r[6], r[7]));
        an = __fadd_rn(l, hh);
    }

    // ---- argmin over this quarter's 128 codes, 8 codes per chunk ----
    const int k0 = __builtin_amdgcn_readfirstlane(h * 128);

    float bd = 1e30f;
    int   bk = 0;
    for (int k = k0; k < k0 + 128; k += 8) {
        const float* e0 = ew + (size_t)k * D;   // wave-uniform -> s_load
        float a0 = 0.f, a1 = 0.f, a2 = 0.f, a3 = 0.f;
        float a4 = 0.f, a5 = 0.f, a6 = 0.f, a7 = 0.f;
        #pragma unroll
        for (int dc = 0; dc < 16; ++dc) {
            float4 zv = zl[dc * TOK + tx[dc & 7]];
            a0 = fmaf(zv.x, e0[4*dc],       a0); a0 = fmaf(zv.y, e0[4*dc+1],       a0);
            a0 = fmaf(zv.z, e0[4*dc+2],     a0); a0 = fmaf(zv.w, e0[4*dc+3],       a0);
            a1 = fmaf(zv.x, e0[D+4*dc],     a1); a1 = fmaf(zv.y, e0[D+4*dc+1],     a1);
            a1 = fmaf(zv.z, e0[D+4*dc+2],   a1); a1 = fmaf(zv.w, e0[D+4*dc+3],     a1);
            a2 = fmaf(zv.x, e0[2*D+4*dc],   a2); a2 = fmaf(zv.y, e0[2*D+4*dc+1],   a2);
            a2 = fmaf(zv.z, e0[2*D+4*dc+2], a2); a2 = fmaf(zv.w, e0[2*D+4*dc+3],   a2);
            a3 = fmaf(zv.x, e0[3*D+4*dc],   a3); a3 = fmaf(zv.y, e0[3*D+4*dc+1],   a3);
            a3 = fmaf(zv.z, e0[3*D+4*dc+2], a3); a3 = fmaf(zv.w, e0[3*D+4*dc+3],   a3);
            a4 = fmaf(zv.x, e0[4*D+4*dc],   a4); a4 = fmaf(zv.y, e0[4*D+4*dc+1],   a4);
            a4 = fmaf(zv.z, e0[4*D+4*dc+2], a4); a4 = fmaf(zv.w, e0[4*D+4*dc+3],   a4);
            a5 = fmaf(zv.x, e0[5*D+4*dc],   a5); a5 = fmaf(zv.y, e0[5*D+4*dc+1],   a5);
            a5 = fmaf(zv.z, e0[5*D+4*dc+2], a5); a5 = fmaf(zv.w, e0[5*D+4*dc+3],   a5);
            a6 = fmaf(zv.x, e0[6*D+4*dc],   a6); a6 = fmaf(zv.y, e0[6*D+4*dc+1],   a6);
            a6 = fmaf(zv.z, e0[6*D+4*dc+2], a6); a6 = fmaf(zv.w, e0[6*D+4*dc+3],   a6);
            a7 = fmaf(zv.x, e0[7*D+4*dc],   a7); a7 = fmaf(zv.y, e0[7*D+4*dc+1],   a7);
            a7 = fmaf(zv.z, e0[7*D+4*dc+2], a7); a7 = fmaf(zv.w, e0[7*D+4*dc+3],   a7);
        }
        // d_k = fl( fl(a + b_k) - 2*g_k ); fmaf(-2,g,t) == fl(t - 2g) exactly
        float d0 = fmaf(-2.f, a0, __fadd_rn(an, b2[k]));
        float d1 = fmaf(-2.f, a1, __fadd_rn(an, b2[k+1]));
        float d2 = fmaf(-2.f, a2, __fadd_rn(an, b2[k+2]));
        float d3 = fmaf(-2.f, a3, __fadd_rn(an, b2[k+3]));
        float d4 = fmaf(-2.f, a4, __fadd_rn(an, b2[k+4]));
        float d5 = fmaf(-2.f, a5, __fadd_rn(an, b2[k+5]));
        float d6 = fmaf(-2.f, a6, __fadd_rn(an, b2[k+6]));
        float d7 = fmaf(-2.f, a7, __fadd_rn(an, b2[k+7]));
        // ascending k, strict <  ->  numpy argmin first-index semantics
        if (d0 < bd) { bd = d0; bk = k;     }
        if (d1 < bd) { bd = d1; bk = k + 1; }
        if (d2 < bd) { bd = d2; bk = k + 2; }
        if (d3 < bd) { bd = d3; bk = k + 3; }
        if (d4 < bd) { bd = d4; bk = k + 4; }
        if (d5 < bd) { bd = d5; bk = k + 5; }
        if (d6 < bd) { bd = d6; bk = k + 6; }
        if (d7 < bd) { bd = d7; bk = k + 7; }
    }

    s_bd[h][t] = bd; s_bk[h][t] = bk;
    __syncthreads();

    if (h == 0) {                              // wave 0 merges (ascending k => first-index ties)
        float fbd = s_bd[0][t]; int fbk = s_bk[0][t];
        #pragma unroll
        for (int q = 1; q < 4; ++q) {
            float qb = s_bd[q][t];
            if (qb < fbd) { fbd = qb; fbk = s_bk[q][t]; }
        }
        s_fbk[t] = fbk;
        atomicAdd(&s_cnt[fbk], 1);

        float mind = fbd;
        #pragma unroll
        for (int off = 32; off; off >>= 1) mind += __shfl_down(mind, off);
        if (t == 0) atomicAdd(&gsum[1], mind);
    }
    __syncthreads();

    // ---- epilogue: 4 threads per token, coalesced-ish writes ----
    {
        const int tok  = tid >> 2;             // 0..63
        const int part = tid & 3;              // dc-quarter
        const int bkf  = s_fbk[tok];
        const float4* eq = (const float4*)(ew + (size_t)bkf * D);
        float4* op = (float4*)(out + Q_OFF + (size_t)(blockIdx.x * TOK + tok) * D);
        float sq = 0.f;
        #pragma unroll
        for (int j = 0; j < 4; ++j) {
            int dc = part * 4 + j;
            float4 zv = zl[dc * TOK + (tok ^ (dc & 7))];
            float4 e = eq[dc];
            float dx = e.x - zv.x, dy = e.y - zv.y;
            float dz = e.z - zv.z, dw = e.w - zv.w;
            sq = fmaf(dx, dx, sq); sq = fmaf(dy, dy, sq);
            sq = fmaf(dz, dz, sq); sq = fmaf(dw, dw, sq);
            float4 o; o.x = zv.x + dx; o.y = zv.y + dy; o.z = zv.z + dz; o.w = zv.w + dw;
            op[dc] = o;
        }
        if (part == 0) out[ENC_OFF + blockIdx.x * TOK + tok] = (float)bkf;

        #pragma unroll
        for (int off = 32; off; off >>= 1) sq += __shfl_down(sq, off);
        if ((tid & 63) == 0) atomicAdd(&gsum[0], sq);
    }

    // ---- flush histogram (s_cnt atomics completed before 2nd barrier) ----
    int c0 = s_cnt[tid];       if (c0) atomicAdd(&gcnt[tid], c0);
    int c1 = s_cnt[tid + BLK]; if (c1) atomicAdd(&gcnt[tid + BLK], c1);
}

__global__ void vq_fin(const float* __restrict__ gsum, const int* __restrict__ gcnt,
                       float* __restrict__ out)
{
    __shared__ float red[8];
    int t = threadIdx.x;               // 512 threads, one per code
    float p = (float)gcnt[t] * (1.f / (float)N_TOK);
    float term = p * logf(p + 1e-10f);
    #pragma unroll
    for (int off = 32; off; off >>= 1) term += __shfl_down(term, off);
    if ((t & 63) == 0) red[t >> 6] = term;
    __syncthreads();
    if (t == 0) {
        float s = 0.f;
        #pragma unroll
        for (int i = 0; i < 8; ++i) s += red[i];
        out[PERP_OFF] = expf(-s);
        out[LOSS_OFF] = 1.25f * gsum[0] * (1.f / (float)(N_TOK * D));
        out[MIND_OFF] = gsum[1] * (1.f / (float)N_TOK);
    }
}

extern "C" void kernel_launch(void* const* d_in, const int* in_sizes, int n_in,
                              void* d_out, int out_size, void* d_ws, size_t ws_size,
                              hipStream_t stream)
{
    const float* z  = (const float*)d_in[0];
    const float* ew = (const float*)d_in[1];
    float* out = (float*)d_out;
    float* wsf = (float*)d_ws;

    float* gsum = wsf + 512;
    int*   gcnt = (int*)(wsf + 514);

    // zero S_sq, S_mind, counts each call (graph replays don't re-poison)
    hipMemsetAsync(wsf + 512, 0, 514 * sizeof(float), stream);

    vq_prep<<<1, 512, 0, stream>>>(ew, wsf);
    vq_main<<<N_TOK / TOK, BLK, 0, stream>>>(z, ew, wsf, out, gsum, gcnt);
    vq_fin<<<1, 512, 0, stream>>>(gsum, gcnt, out);
}

// Round 7
// 182.996 us; speedup vs baseline: 1.3013x; 1.3013x over previous
//
#include <hip/hip_runtime.h>
#include <math.h>

#define D 64
#define K 512
#define N_TOK (32 * 4096)            // 131072 tokens
#define TOK 64                       // tokens per block
#define BLK 256                      // 4 waves = 4 k-quarters

// output layout (all f32, concatenated in reference return order)
#define Q_OFF    0
#define LOSS_OFF 8388608
#define PERP_OFF 8388609
#define ENC_OFF  8388610
#define MIND_OFF 8519682

// ws layout (floats): [0..511] b2[k] = np-f32 sum(e_k^2) ; [512] S_sq ; [513] S_mind ; [514..1025] counts(int)

// numpy pairwise_sum, n=64, scalar 8-accumulator path, on fl(x_i*x_i).
__device__ __forceinline__ float np_sumsq64(const float* x) {
    float r[8];
    #pragma unroll
    for (int j = 0; j < 8; ++j) r[j] = __fmul_rn(x[j], x[j]);
    #pragma unroll
    for (int i = 8; i < 64; i += 8) {
        #pragma unroll
        for (int j = 0; j < 8; ++j)
            r[j] = __fadd_rn(r[j], __fmul_rn(x[i + j], x[i + j]));
    }
    float l = __fadd_rn(__fadd_rn(r[0], r[1]), __fadd_rn(r[2], r[3]));
    float h = __fadd_rn(__fadd_rn(r[4], r[5]), __fadd_rn(r[6], r[7]));
    return __fadd_rn(l, h);
}

__global__ void vq_prep(const float* __restrict__ ew, float* __restrict__ b2) {
    int k = threadIdx.x;
    if (k < K) b2[k] = np_sumsq64(ew + (size_t)k * D);
}

// z row lives in VGPRs, pinned with asm so the allocator cannot
// rematerialize it from global inside the k-loop (rounds 3/4 showed it
// will at any launch-bounds setting). Codebook stays wave-uniform ->
// s_load broadcast; the k-loop has NO vector-memory and NO LDS ops, so
// the only lgkmcnt waits are the s_loads themselves, hidden across
// 5 resident waves/SIMD. Wave id = k-quarter (wave-uniform split).
__global__ __launch_bounds__(BLK, 5) void vq_main(
    const float* __restrict__ z, const float* __restrict__ ew,
    const float* __restrict__ b2, float* __restrict__ out,
    float* __restrict__ gsum, int* __restrict__ gcnt)
{
    __shared__ float s_bd[4][TOK];
    __shared__ int   s_bk[4][TOK];
    __shared__ int   s_fbk[TOK];
    __shared__ int   s_cnt[K];

    const int tid = threadIdx.x;
    const int q   = tid >> 6;                  // wave id = k-quarter (uniform)
    const int t   = tid & 63;                  // token within block
    const int token = blockIdx.x * TOK + t;

    s_cnt[tid] = 0; s_cnt[tid + BLK] = 0;

    // ---- token's z row into registers ----
    float zr[D];
    {
        const float4* zp = (const float4*)(z + (size_t)token * D);
        #pragma unroll
        for (int i = 0; i < 16; ++i) {
            float4 v = zp[i];
            zr[4*i] = v.x; zr[4*i+1] = v.y; zr[4*i+2] = v.z; zr[4*i+3] = v.w;
        }
    }
    // pin: values become asm-defined -> not rematerializable, stay in VGPRs
    #pragma unroll
    for (int d = 0; d < D; ++d) asm volatile("" : "+v"(zr[d]));

    // a_n = np.sum(z^2) in numpy's exact f32 order
    const float an = np_sumsq64(zr);

    // ---- argmin over this quarter's 128 codes ----
    const int k0 = __builtin_amdgcn_readfirstlane(q * 128);

    float bd = 1e30f;
    int   bk = 0;
    for (int k = k0; k < k0 + 128; k += 4) {
        const float* e0 = ew + (size_t)k * D;   // wave-uniform -> s_load
        float a0 = 0.f, a1 = 0.f, a2 = 0.f, a3 = 0.f;
        #pragma unroll
        for (int d = 0; d < D; ++d) {
            a0 = fmaf(zr[d], e0[d],       a0);
            a1 = fmaf(zr[d], e0[D + d],   a1);
            a2 = fmaf(zr[d], e0[2*D + d], a2);
            a3 = fmaf(zr[d], e0[3*D + d], a3);
        }
        // d_k = fl( fl(a + b_k) - 2*g_k ); fmaf(-2,g,t) == fl(t - 2g) exactly
        float d0 = fmaf(-2.f, a0, __fadd_rn(an, b2[k]));
        float d1 = fmaf(-2.f, a1, __fadd_rn(an, b2[k+1]));
        float d2 = fmaf(-2.f, a2, __fadd_rn(an, b2[k+2]));
        float d3 = fmaf(-2.f, a3, __fadd_rn(an, b2[k+3]));
        // ascending k, strict <  ->  numpy argmin first-index semantics
        if (d0 < bd) { bd = d0; bk = k;     }
        if (d1 < bd) { bd = d1; bk = k + 1; }
        if (d2 < bd) { bd = d2; bk = k + 2; }
        if (d3 < bd) { bd = d3; bk = k + 3; }
    }

    s_bd[q][t] = bd; s_bk[q][t] = bk;
    __syncthreads();                           // also covers s_cnt init

    if (q == 0) {                              // ascending q = ascending k => first-index ties
        float fbd = s_bd[0][t]; int fbk = s_bk[0][t];
        #pragma unroll
        for (int qq = 1; qq < 4; ++qq) {
            float qb = s_bd[qq][t];
            if (qb < fbd) { fbd = qb; fbk = s_bk[qq][t]; }
        }
        s_fbk[t] = fbk;
        atomicAdd(&s_cnt[fbk], 1);

        float mind = fbd;
        #pragma unroll
        for (int off = 32; off; off >>= 1) mind += __shfl_down(mind, off);
        if (t == 0) atomicAdd(&gsum[1], mind);
    }
    __syncthreads();                           // s_fbk + s_cnt final

    if (q == 0) {
        // epilogue from in-register z row (compile-time zr indices only)
        const int bkf = s_fbk[t];
        const float4* eq = (const float4*)(ew + (size_t)bkf * D);
        float4* op = (float4*)(out + Q_OFF + (size_t)token * D);
        float sq = 0.f;
        #pragma unroll
        for (int i = 0; i < 16; ++i) {
            float4 e = eq[i];
            float zx = zr[4*i], zy = zr[4*i+1], zz = zr[4*i+2], zw = zr[4*i+3];
            float dx = e.x - zx, dy = e.y - zy, dz = e.z - zz, dw = e.w - zw;
            sq = fmaf(dx, dx, sq); sq = fmaf(dy, dy, sq);
            sq = fmaf(dz, dz, sq); sq = fmaf(dw, dw, sq);
            float4 o; o.x = zx + dx; o.y = zy + dy; o.z = zz + dz; o.w = zw + dw;
            op[i] = o;
        }
        out[ENC_OFF + token] = (float)bkf;

        #pragma unroll
        for (int off = 32; off; off >>= 1) sq += __shfl_down(sq, off);
        if (t == 0) atomicAdd(&gsum[0], sq);
    }

    // ---- flush histogram ----
    int c0 = s_cnt[tid];       if (c0) atomicAdd(&gcnt[tid], c0);
    int c1 = s_cnt[tid + BLK]; if (c1) atomicAdd(&gcnt[tid + BLK], c1);
}

__global__ void vq_fin(const float* __restrict__ gsum, const int* __restrict__ gcnt,
                       float* __restrict__ out)
{
    __shared__ float red[8];
    int t = threadIdx.x;               // 512 threads, one per code
    float p = (float)gcnt[t] * (1.f / (float)N_TOK);
    float term = p * logf(p + 1e-10f);
    #pragma unroll
    for (int off = 32; off; off >>= 1) term += __shfl_down(term, off);
    if ((t & 63) == 0) red[t >> 6] = term;
    __syncthreads();
    if (t == 0) {
        float s = 0.f;
        #pragma unroll
        for (int i = 0; i < 8; ++i) s += red[i];
        out[PERP_OFF] = expf(-s);
        out[LOSS_OFF] = 1.25f * gsum[0] * (1.f / (float)(N_TOK * D));
        out[MIND_OFF] = gsum[1] * (1.f / (float)N_TOK);
    }
}

extern "C" void kernel_launch(void* const* d_in, const int* in_sizes, int n_in,
                              void* d_out, int out_size, void* d_ws, size_t ws_size,
                              hipStream_t stream)
{
    const float* z  = (const float*)d_in[0];
    const float* ew = (const float*)d_in[1];
    float* out = (float*)d_out;
    float* wsf = (float*)d_ws;

    float* gsum = wsf + 512;
    int*   gcnt = (int*)(wsf + 514);

    // zero S_sq, S_mind, counts each call (graph replays don't re-poison)
    hipMemsetAsync(wsf + 512, 0, 514 * sizeof(float), stream);

    vq_prep<<<1, 512, 0, stream>>>(ew, wsf);
    vq_main<<<N_TOK / TOK, BLK, 0, stream>>>(z, ew, wsf, out, gsum, gcnt);
    vq_fin<<<1, 512, 0, stream>>>(gsum, gcnt, out);
}